// Round 5
// baseline (174.009 us; speedup 1.0000x reference)
//
#include <hip/hip_runtime.h>

// CASREL loss, B=32,S=512,H=1024,R=64 -> scalar fp32 loss.
// v6: counted-vmcnt pipeline (T4). All staging is global_load_lds DMA:
//   A staged as fp32 (linear LDS dest, XOR-swizzled source; f2bf at read time)
//   B staged bf16 as in v5 (verified).
// Raw s_barrier + asm s_waitcnt vmcnt(3/2): chunk t+1's loads stay in flight
// across the barrier (no vmcnt(0) drain - the v3-v5 ceiling). Bit-identical
// math to v5. aux_kernel unchanged from v4/v5.

#define B_  32
#define S_  512
#define H_  1024
#define R_  64
#define M_  (B_ * S_)      // 16384 rows
#define NPAD 160           // 130 valid cols padded
#define NVALID 130
#define BK 64
#define MT 32              // rows per block
#define NCHUNK (H_ / BK)   // 16
#define TBLK 20            // transpose blocks (5 n-tiles x 4 k-tiles)
#define NTHR 640           // 10 waves

typedef __attribute__((ext_vector_type(4))) float  floatx4;
typedef __attribute__((ext_vector_type(8))) short  short8;     // 8 bf16
typedef __attribute__((ext_vector_type(4))) unsigned short u16x4;
typedef __attribute__((ext_vector_type(8))) unsigned short u16x8;

__device__ __forceinline__ unsigned short f2bf(float f) {
    unsigned int u = __float_as_uint(f);
    u = (u + 0x7FFFu + ((u >> 16) & 1u)) >> 16;   // RNE
    return (unsigned short)u;
}

__device__ __forceinline__ short8 cvt8(float4 a, float4 b) {
    union { unsigned short us[8]; short8 s8; } u;
    u.us[0] = f2bf(a.x); u.us[1] = f2bf(a.y); u.us[2] = f2bf(a.z); u.us[3] = f2bf(a.w);
    u.us[4] = f2bf(b.x); u.us[5] = f2bf(b.y); u.us[6] = f2bf(b.z); u.us[7] = f2bf(b.w);
    return u.s8;
}

__device__ __forceinline__ void gload16(const void* g, void* l) {
    __builtin_amdgcn_global_load_lds(
        (const __attribute__((address_space(1))) unsigned int*)g,
        (__attribute__((address_space(3))) unsigned int*)l, 16, 0, 0);
}

// ---- K1 (merged): blocks [0,TBLK) transpose WtG; blocks [TBLK,TBLK+B_) subj ----
__global__ __launch_bounds__(256) void aux_kernel(
        const float* __restrict__ ctx, const float* __restrict__ head,
        const float* __restrict__ tail, const float* __restrict__ masks,
        const float* __restrict__ Wo_h, const float* __restrict__ Wo_t,
        const float* __restrict__ Ws_h, const float* __restrict__ Ws_t,
        const float* __restrict__ bo_h, const float* __restrict__ bo_t,
        const float* __restrict__ bs_h, const float* __restrict__ bs_t,
        unsigned short* __restrict__ WtG, float* __restrict__ rowBias,
        float* __restrict__ accum) {
    const int tid = threadIdx.x;
    __shared__ float tr[32][257];      // transpose tile (pad 257: conflict-free)
    __shared__ float subj[H_];
    __shared__ float partS[4][256];
    __shared__ int cnt;
    __shared__ int   sidx[8];
    __shared__ float sw[8];

    if (blockIdx.x < TBLK) {
        const int kt = blockIdx.x / 5, nt = blockIdx.x % 5;
        const int k0 = kt * 256, n0 = nt * 32;
        if (n0 < 128) {
            const float* src = (n0 < 64) ? Wo_h : Wo_t;
            const int cb = n0 & 63;
            const int nn = tid & 31, kk = tid >> 5;   // 8 k-rows per pass
#pragma unroll
            for (int i = 0; i < 32; ++i) {
                const int k = k0 + i * 8 + kk;
                tr[nn][i * 8 + kk] = src[(size_t)k * R_ + cb + nn];
            }
            __syncthreads();
#pragma unroll
            for (int p = 0; p < 4; ++p) {
                const int chunk = p * 256 + tid;
                const int n = chunk >> 5;             // 0..31
                const int kc = (chunk & 31) * 8;
                u16x8 v;
#pragma unroll
                for (int j = 0; j < 8; ++j) v[j] = f2bf(tr[n][kc + j]);
                *(u16x8*)(WtG + (size_t)(n0 + n) * H_ + k0 + kc) = v;
            }
        } else {
#pragma unroll
            for (int p = 0; p < 4; ++p) {
                const int chunk = p * 256 + tid;
                const int n = 128 + (chunk >> 5);
                const int kc = (chunk & 31) * 8;
                u16x8 v;
#pragma unroll
                for (int j = 0; j < 8; ++j) {
                    float f = (n == 128) ? Ws_h[k0 + kc + j]
                            : (n == 129) ? Ws_t[k0 + kc + j] : 0.0f;
                    v[j] = f2bf(f);
                }
                *(u16x8*)(WtG + (size_t)n * H_ + k0 + kc) = v;
            }
        }
        return;
    }

    const int b = blockIdx.x - TBLK;
    if (tid == 0) cnt = 0;
    __syncthreads();
    float msk = 0.0f;
    for (int s = tid; s < S_; s += 256) {
        float w = 0.5f * (head[b * S_ + s] + tail[b * S_ + s]);
        if (w != 0.0f) {
            int i = atomicAdd(&cnt, 1);
            if (i < 8) { sidx[i] = s; sw[i] = w; }
        }
        msk += masks[b * S_ + s];
    }
    for (int o = 32; o > 0; o >>= 1) msk += __shfl_down(msk, o, 64);
    if ((tid & 63) == 0) atomicAdd(&accum[1], msk);
    __syncthreads();
    const int nnz = cnt < 8 ? cnt : 8;
    for (int h = tid; h < H_; h += 256) {
        float a = 0.0f;
        for (int i = 0; i < nnz; i++)
            a += sw[i] * ctx[((size_t)b * S_ + sidx[i]) * H_ + h];
        subj[h] = a;
    }
    __syncthreads();
    {   // rowBias dot: thread = (c-group of 4, k-slice of 128); float4 W loads
        const int cg = tid & 31;
        const int ks = tid >> 5;
        const int c4 = cg * 4;
        const float* W = (c4 < 64) ? Wo_h : Wo_t;
        const int cc = c4 & 63;
        const int kk0 = ks * 128;
        float ax = 0.f, ay = 0.f, az = 0.f, aw2 = 0.f;
#pragma unroll 4
        for (int k = kk0; k < kk0 + 128; ++k) {
            const float4 w = *(const float4*)(W + (size_t)k * R_ + cc);
            const float sv = subj[k];
            ax += sv * w.x; ay += sv * w.y; az += sv * w.z; aw2 += sv * w.w;
        }
        partS[0][tid] = ax; partS[1][tid] = ay;
        partS[2][tid] = az; partS[3][tid] = aw2;
    }
    __syncthreads();
    if (tid < NPAD) {
        float bias = tid < 64  ? bo_h[tid]
                   : tid < 128 ? bo_t[tid - 64]
                   : tid == 128 ? bs_h[0]
                   : tid == 129 ? bs_t[0] : 0.0f;
        float a2 = 0.0f;
        if (tid < 128) {
            const int g = tid >> 2, j = tid & 3;
#pragma unroll
            for (int s = 0; s < 8; ++s) a2 += partS[j][s * 32 + g];
        }
        rowBias[b * NPAD + tid] = bias + a2;
    }
}

// ---- K2: counted-vmcnt pipelined GEMM + BCE + masked reduction + finalize ----
__global__ __launch_bounds__(NTHR, 5) void main_kernel(
        const float* __restrict__ ctx, const unsigned short* __restrict__ WtG,
        const float* __restrict__ rowBias, const float* __restrict__ masks,
        const float* __restrict__ ash, const float* __restrict__ ast,
        const float* __restrict__ oh, const float* __restrict__ ot,
        float* __restrict__ accum, float* __restrict__ out) {
    __shared__ __align__(16) float          AsmF[2][MT * BK];    // 16 KB fp32 A
    __shared__ __align__(16) unsigned short Bsm[2][NPAD * BK];   // 40 KB bf16 B
    __shared__ float rbuf[10];

    const int tid  = threadIdx.x;
    const int gm0  = blockIdx.x * MT;
    const int b    = gm0 >> 9;
    const int wave = tid >> 6, lane = tid & 63;
    const int wm = wave & 1;            // row half (16 rows)
    const int wn = wave >> 1;           // col group of 32 (2 tiles), 0..4
    const int lr = lane & 15, q = lane >> 4;   // q in 0..3

    // ---- A staging map (fp32 DMA, linear LDS dest, source XOR-swizzled) ----
    // thread s (<512): LDS bytes s*16 <- G[row = s>>4][ ((s&15)*16) ^ ((row&7)<<4) ]
    const bool aw = (tid < 512);
    const int  as_  = tid & 511;
    const int  arow = as_ >> 4;
    const float* aSrcG = ctx + (size_t)(gm0 + arow) * H_
                       + (((((as_ & 15) * 16)) ^ ((arow & 7) << 4)) >> 2);
    const int  aDstF = arow * BK + (as_ & 15) * 4;          // float index

    // ---- B staging map (bf16 DMA, as v5, verified) ----
    const int br = tid >> 3, bc = (tid & 7) * 16;           // br 0..79
    const unsigned short* bSrcG = WtG + (size_t)br * H_ + ((bc ^ ((br & 7) << 4)) >> 1);
    const int bDstS = br * BK + (bc >> 1);                  // short index; +5120 for p=1

    // ---- compute-side fragment offsets ----
    const int aRow  = wm * 16 + lr;
    const int aBase = aRow * 256;                           // byte base of fp32 row
    const int aSw   = (aRow & 7) << 4;
    int bOff[2];
#pragma unroll
    for (int tt = 0; tt < 2; ++tt) {
        const int row = wn * 32 + tt * 16 + lr;
        bOff[tt] = row * 128 + ((q * 16) ^ ((row & 7) << 4));   // bytes; ^(kk<<1) per substep
    }

    floatx4 acc[2];
#pragma unroll
    for (int tt = 0; tt < 2; ++tt) acc[tt] = (floatx4){0.f, 0.f, 0.f, 0.f};

#define STAGE(bufi, koff) do {                                                 \
        gload16(bSrcG + (koff), &Bsm[bufi][bDstS]);                            \
        gload16(bSrcG + 80 * H_ + (koff), &Bsm[bufi][5120 + bDstS]);           \
        if (aw) gload16(aSrcG + (koff), &AsmF[bufi][aDstF]);                   \
    } while (0)

#define COMPUTE(bufi) do {                                                     \
        const char* Acp = (const char*)&AsmF[bufi][0];                         \
        const char* Bcp = (const char*)&Bsm[bufi][0];                          \
        _Pragma("unroll")                                                      \
        for (int kk = 0; kk < BK; kk += 32) {                                  \
            const int ia = kk * 4 + q * 32;                                    \
            const float4 f0 = *(const float4*)(Acp + aBase + (ia ^ aSw));      \
            const float4 f1 = *(const float4*)(Acp + aBase + ((ia + 16) ^ aSw));\
            const short8 afr = cvt8(f0, f1);                                   \
            _Pragma("unroll")                                                  \
            for (int tt = 0; tt < 2; ++tt) {                                   \
                const short8 bfr = *(const short8*)(Bcp + (bOff[tt] ^ (kk << 1)));\
                acc[tt] = __builtin_amdgcn_mfma_f32_16x16x32_bf16(afr, bfr, acc[tt], 0, 0, 0);\
            }                                                                  \
        }                                                                      \
    } while (0)

    // prologue: chunk 0 in flight
    STAGE(0, 0);

    for (int t = 0; t < NCHUNK - 1; ++t) {
        const int cur = t & 1;
        STAGE(cur ^ 1, (t + 1) * BK);          // chunk t+1 -> other buffer
        // wait ONLY for chunk t's loads (issued one full iteration ago);
        // chunk t+1's (3 or 2 newest per wave) stay in flight across the barrier
        if (aw) asm volatile("s_waitcnt vmcnt(3)" ::: "memory");
        else    asm volatile("s_waitcnt vmcnt(2)" ::: "memory");
        __builtin_amdgcn_s_barrier();
        __builtin_amdgcn_sched_barrier(0);
        COMPUTE(cur);
        asm volatile("s_waitcnt lgkmcnt(0)" ::: "memory");
        __builtin_amdgcn_s_barrier();          // reads done before next overwrite
    }
    // last chunk
    asm volatile("s_waitcnt vmcnt(0)" ::: "memory");
    __builtin_amdgcn_s_barrier();
    __builtin_amdgcn_sched_barrier(0);
    COMPUTE((NCHUNK - 1) & 1);

    // epilogue: logits -> BCE * mask -> sum
    float lsum = 0.0f;
#pragma unroll
    for (int tt = 0; tt < 2; ++tt) {
        const int col = wn * 32 + tt * 16 + lr;
        if (col < NVALID) {
            const float rb = rowBias[b * NPAD + col];
#pragma unroll
            for (int i = 0; i < 4; ++i) {
                const int row = gm0 + wm * 16 + q * 4 + i;
                const float l = acc[tt][i] + rb;
                float tgt;
                if (col < 64)        tgt = oh[(size_t)row * R_ + col];
                else if (col < 128)  tgt = ot[(size_t)row * R_ + (col - 64)];
                else if (col == 128) tgt = ash[row];
                else                 tgt = ast[row];
                const float mk = masks[row];
                const float bce = fmaxf(l, 0.0f) - l * tgt + log1pf(__expf(-fabsf(l)));
                lsum += bce * mk;
            }
        }
    }
    for (int o = 32; o > 0; o >>= 1) lsum += __shfl_down(lsum, o, 64);
    if (lane == 0) rbuf[wave] = lsum;
    __syncthreads();
    if (tid == 0) {
        float s0 = 0.0f;
#pragma unroll
        for (int w = 0; w < 10; ++w) s0 += rbuf[w];
        atomicAdd(&accum[0], s0);
        __threadfence();
        const unsigned int prev = atomicAdd((unsigned int*)(accum + 2), 1u);
        if (prev == gridDim.x - 1) {   // last block finalizes
            const float s = atomicAdd(&accum[0], 0.0f);
            const float m = atomicAdd(&accum[1], 0.0f);
            out[0] = s / m;
        }
    }
#undef STAGE
#undef COMPUTE
}

extern "C" void kernel_launch(void* const* d_in, const int* in_sizes, int n_in,
                              void* d_out, int out_size, void* d_ws, size_t ws_size,
                              hipStream_t stream) {
    const float* ctx   = (const float*)d_in[0];
    const float* masks = (const float*)d_in[1];
    const float* ash   = (const float*)d_in[2];
    const float* ast   = (const float*)d_in[3];
    const float* sh    = (const float*)d_in[4];
    const float* st    = (const float*)d_in[5];
    const float* oh    = (const float*)d_in[6];
    const float* ot    = (const float*)d_in[7];
    const float* Ws_h  = (const float*)d_in[8];
    const float* bs_h  = (const float*)d_in[9];
    const float* Ws_t  = (const float*)d_in[10];
    const float* bs_t  = (const float*)d_in[11];
    const float* Wo_h  = (const float*)d_in[12];
    const float* bo_h  = (const float*)d_in[13];
    const float* Wo_t  = (const float*)d_in[14];
    const float* bo_t  = (const float*)d_in[15];
    float* out = (float*)d_out;

    char* ws = (char*)d_ws;
    float* accum   = (float*)(ws + 0);                 // [0]=loss, [1]=msum, [2]=counter
    float* rowBias = (float*)(ws + 256);               // [32][160] fp32
    unsigned short* WtG = (unsigned short*)(ws + 256 + 32 * NPAD * 4); // [160][1024] bf16

    hipMemsetAsync(accum, 0, 12, stream);
    aux_kernel<<<TBLK + B_, 256, 0, stream>>>(ctx, sh, st, masks, Wo_h, Wo_t,
                                              Ws_h, Ws_t, bo_h, bo_t, bs_h, bs_t,
                                              WtG, rowBias, accum);
    main_kernel<<<M_ / MT, NTHR, 0, stream>>>(ctx, WtG, rowBias, masks,
                                              ash, ast, oh, ot, accum, out);
}

// Round 6
// 165.441 us; speedup vs baseline: 1.0518x; 1.0518x over previous
//
#include <hip/hip_runtime.h>

// CASREL loss, B=32,S=512,H=1024,R=64 -> scalar fp32 loss.
// v7: round-count reduction. Model from v1-v6: kernel is barrier-round-bound
// (~2500cy/round); occupancy (v5) and manual vmcnt pipelines (v6) don't help.
// So: BK 64->128 halves the rounds (8 chunks x 2 barriers), through-VGPR
// staging with plain __syncthreads (the only scheme the compiler schedules
// well - v1 evidence), next-chunk loads issued before barrier(b) so latency
// hides under barrier-wait + the 2x-longer compute phase. B uses the
// v4-verified XOR-swizzle LDS layout; A uses pad-136. Same K order as v1-v6.

#define B_  32
#define S_  512
#define H_  1024
#define R_  64
#define M_  (B_ * S_)      // 16384 rows
#define NPAD 160           // 130 valid cols padded
#define NVALID 130
#define BK 128
#define BKP 136            // A LDS pad (shorts)
#define MT 32              // rows per block
#define NCHUNK (H_ / BK)   // 8
#define TBLK 20            // transpose blocks (5 n-tiles x 4 k-tiles)

typedef __attribute__((ext_vector_type(4))) float  floatx4;
typedef __attribute__((ext_vector_type(8))) short  short8;     // 8 bf16
typedef __attribute__((ext_vector_type(4))) unsigned short u16x4;
typedef __attribute__((ext_vector_type(8))) unsigned short u16x8;

__device__ __forceinline__ unsigned short f2bf(float f) {
    unsigned int u = __float_as_uint(f);
    u = (u + 0x7FFFu + ((u >> 16) & 1u)) >> 16;   // RNE
    return (unsigned short)u;
}

__device__ __forceinline__ u16x8 cvt8u(float4 a, float4 b) {
    u16x8 u;
    u[0] = f2bf(a.x); u[1] = f2bf(a.y); u[2] = f2bf(a.z); u[3] = f2bf(a.w);
    u[4] = f2bf(b.x); u[5] = f2bf(b.y); u[6] = f2bf(b.z); u[7] = f2bf(b.w);
    return u;
}

// ---- K1 (merged): blocks [0,TBLK) transpose WtG; blocks [TBLK,TBLK+B_) subj ----
__global__ __launch_bounds__(256) void aux_kernel(
        const float* __restrict__ ctx, const float* __restrict__ head,
        const float* __restrict__ tail, const float* __restrict__ masks,
        const float* __restrict__ Wo_h, const float* __restrict__ Wo_t,
        const float* __restrict__ Ws_h, const float* __restrict__ Ws_t,
        const float* __restrict__ bo_h, const float* __restrict__ bo_t,
        const float* __restrict__ bs_h, const float* __restrict__ bs_t,
        unsigned short* __restrict__ WtG, float* __restrict__ rowBias,
        float* __restrict__ accum) {
    const int tid = threadIdx.x;
    __shared__ float tr[32][257];      // transpose tile (pad 257: conflict-free)
    __shared__ float subj[H_];
    __shared__ float partS[4][256];
    __shared__ int cnt;
    __shared__ int   sidx[8];
    __shared__ float sw[8];

    if (blockIdx.x < TBLK) {
        const int kt = blockIdx.x / 5, nt = blockIdx.x % 5;
        const int k0 = kt * 256, n0 = nt * 32;
        if (n0 < 128) {
            const float* src = (n0 < 64) ? Wo_h : Wo_t;
            const int cb = n0 & 63;
            const int nn = tid & 31, kk = tid >> 5;   // 8 k-rows per pass
#pragma unroll
            for (int i = 0; i < 32; ++i) {
                const int k = k0 + i * 8 + kk;
                tr[nn][i * 8 + kk] = src[(size_t)k * R_ + cb + nn];
            }
            __syncthreads();
#pragma unroll
            for (int p = 0; p < 4; ++p) {
                const int chunk = p * 256 + tid;
                const int n = chunk >> 5;             // 0..31
                const int kc = (chunk & 31) * 8;
                u16x8 v;
#pragma unroll
                for (int j = 0; j < 8; ++j) v[j] = f2bf(tr[n][kc + j]);
                *(u16x8*)(WtG + (size_t)(n0 + n) * H_ + k0 + kc) = v;
            }
        } else {
#pragma unroll
            for (int p = 0; p < 4; ++p) {
                const int chunk = p * 256 + tid;
                const int n = 128 + (chunk >> 5);
                const int kc = (chunk & 31) * 8;
                u16x8 v;
#pragma unroll
                for (int j = 0; j < 8; ++j) {
                    float f = (n == 128) ? Ws_h[k0 + kc + j]
                            : (n == 129) ? Ws_t[k0 + kc + j] : 0.0f;
                    v[j] = f2bf(f);
                }
                *(u16x8*)(WtG + (size_t)n * H_ + k0 + kc) = v;
            }
        }
        return;
    }

    const int b = blockIdx.x - TBLK;
    if (tid == 0) cnt = 0;
    __syncthreads();
    float msk = 0.0f;
    for (int s = tid; s < S_; s += 256) {
        float w = 0.5f * (head[b * S_ + s] + tail[b * S_ + s]);
        if (w != 0.0f) {
            int i = atomicAdd(&cnt, 1);
            if (i < 8) { sidx[i] = s; sw[i] = w; }
        }
        msk += masks[b * S_ + s];
    }
    for (int o = 32; o > 0; o >>= 1) msk += __shfl_down(msk, o, 64);
    if ((tid & 63) == 0) atomicAdd(&accum[1], msk);
    __syncthreads();
    const int nnz = cnt < 8 ? cnt : 8;
    for (int h = tid; h < H_; h += 256) {
        float a = 0.0f;
        for (int i = 0; i < nnz; i++)
            a += sw[i] * ctx[((size_t)b * S_ + sidx[i]) * H_ + h];
        subj[h] = a;
    }
    __syncthreads();
    {   // rowBias dot: thread = (c-group of 4, k-slice of 128); float4 W loads
        const int cg = tid & 31;
        const int ks = tid >> 5;
        const int c4 = cg * 4;
        const float* W = (c4 < 64) ? Wo_h : Wo_t;
        const int cc = c4 & 63;
        const int kk0 = ks * 128;
        float ax = 0.f, ay = 0.f, az = 0.f, aw2 = 0.f;
#pragma unroll 4
        for (int k = kk0; k < kk0 + 128; ++k) {
            const float4 w = *(const float4*)(W + (size_t)k * R_ + cc);
            const float sv = subj[k];
            ax += sv * w.x; ay += sv * w.y; az += sv * w.z; aw2 += sv * w.w;
        }
        partS[0][tid] = ax; partS[1][tid] = ay;
        partS[2][tid] = az; partS[3][tid] = aw2;
    }
    __syncthreads();
    if (tid < NPAD) {
        float bias = tid < 64  ? bo_h[tid]
                   : tid < 128 ? bo_t[tid - 64]
                   : tid == 128 ? bs_h[0]
                   : tid == 129 ? bs_t[0] : 0.0f;
        float a2 = 0.0f;
        if (tid < 128) {
            const int g = tid >> 2, j = tid & 3;
#pragma unroll
            for (int s = 0; s < 8; ++s) a2 += partS[j][s * 32 + g];
        }
        rowBias[b * NPAD + tid] = bias + a2;
    }
}

// ---- K2: BK=128 single-buffer GEMM + BCE + masked reduction + finalize ----
__global__ __launch_bounds__(256, 2) void main_kernel(
        const float* __restrict__ ctx, const unsigned short* __restrict__ WtG,
        const float* __restrict__ rowBias, const float* __restrict__ masks,
        const float* __restrict__ ash, const float* __restrict__ ast,
        const float* __restrict__ oh, const float* __restrict__ ot,
        float* __restrict__ accum, float* __restrict__ out) {
    __shared__ __align__(16) unsigned short Asm[MT * BKP];   // 8.7 KB
    __shared__ __align__(16) unsigned short Bsm[NPAD * BK];  // 40 KB
    __shared__ float rbuf[4];

    const int tid  = threadIdx.x;
    const int gm0  = blockIdx.x * MT;
    const int b    = gm0 >> 9;
    const int wave = tid >> 6, lane = tid & 63;
    const int wm = wave & 1;            // row half (16 rows)
    const int wn = wave >> 1;           // col half (80 cols = 5 tiles)
    const int lr = lane & 15, q = lane >> 4;   // q in 0..3

    // A staging: thread -> row ar = tid>>3, 16 floats at col (tid&7)*16
    const int ar = tid >> 3, as_ = (tid & 7) * 16;
    const float* aSrc = ctx + (size_t)(gm0 + ar) * H_ + as_;
    unsigned short* aDst = &Asm[ar * BKP + as_];

    // B staging: 5 passes of 32 rows; thread -> row br, 16 shorts at (tid&7)*16
    // LDS layout: [row][128] shorts, byte col XOR-swizzled by ((row&7)<<4)
    const int br = tid >> 3, bs0 = (tid & 7) * 16;   // shorts
    const unsigned short* bSrc = WtG + (size_t)br * H_ + bs0;
    const int bswz = (br & 7) << 4;                  // same all passes (32%8==0)
    char* bDstB = (char*)Bsm + br * 256;             // + ((bytecol)^bswz)

    // compute-side fragment offsets
    const int aOff = (wm * 16 + lr) * BKP + q * 8;   // shorts
    int bOff[5];
#pragma unroll
    for (int tt = 0; tt < 5; ++tt) {
        const int row = wn * 80 + tt * 16 + lr;
        bOff[tt] = row * 256 + ((q * 16) ^ ((row & 7) << 4));   // bytes; ^(kk<<1) per substep
    }

    floatx4 acc[5];
#pragma unroll
    for (int tt = 0; tt < 5; ++tt) acc[tt] = (floatx4){0.f, 0.f, 0.f, 0.f};

    // staging registers for one chunk
    float4 aR[4];
    u16x8  bR[10];

#define LOADREGS(k0) do {                                                      \
        _Pragma("unroll")                                                      \
        for (int i = 0; i < 4; ++i)                                            \
            aR[i] = *(const float4*)(aSrc + (k0) + i * 4);                     \
        _Pragma("unroll")                                                      \
        for (int p = 0; p < 5; ++p) {                                          \
            bR[2*p]   = *(const u16x8*)(bSrc + (size_t)(p*32) * H_ + (k0));    \
            bR[2*p+1] = *(const u16x8*)(bSrc + (size_t)(p*32) * H_ + (k0) + 8);\
        }                                                                      \
    } while (0)

#define WRITE_LDS() do {                                                       \
        *(u16x8*)(aDst)     = cvt8u(aR[0], aR[1]);                             \
        *(u16x8*)(aDst + 8) = cvt8u(aR[2], aR[3]);                             \
        _Pragma("unroll")                                                      \
        for (int p = 0; p < 5; ++p) {                                          \
            *(u16x8*)(bDstB + p * 32 * 256 + ((bs0 * 2)      ^ bswz)) = bR[2*p];   \
            *(u16x8*)(bDstB + p * 32 * 256 + ((bs0 * 2 + 16) ^ bswz)) = bR[2*p+1]; \
        }                                                                      \
    } while (0)

    LOADREGS(0);
    for (int t = 0; t < NCHUNK; ++t) {
        __syncthreads();                 // (a) prior chunk's LDS reads done
        WRITE_LDS();
        if (t < NCHUNK - 1) LOADREGS((t + 1) * BK);   // issue next loads now
        __syncthreads();                 // (b) LDS writes visible
        // compute chunk t (loads for t+1 in flight under this)
#pragma unroll
        for (int kk = 0; kk < BK; kk += 32) {
            short8 afr = *(const short8*)&Asm[aOff + kk];
#pragma unroll
            for (int tt = 0; tt < 5; ++tt) {
                short8 bfr = *(const short8*)((const char*)Bsm + (bOff[tt] ^ (kk << 1)));
                acc[tt] = __builtin_amdgcn_mfma_f32_16x16x32_bf16(afr, bfr, acc[tt], 0, 0, 0);
            }
        }
    }
#undef LOADREGS
#undef WRITE_LDS

    // epilogue: logits -> BCE * mask -> sum
    float lsum = 0.0f;
#pragma unroll
    for (int tt = 0; tt < 5; ++tt) {
        const int col = wn * 80 + tt * 16 + lr;
        if (col < NVALID) {
            const float rb = rowBias[b * NPAD + col];
#pragma unroll
            for (int i = 0; i < 4; ++i) {
                const int row = gm0 + wm * 16 + q * 4 + i;
                const float l = acc[tt][i] + rb;
                float tgt;
                if (col < 64)        tgt = oh[(size_t)row * R_ + col];
                else if (col < 128)  tgt = ot[(size_t)row * R_ + (col - 64)];
                else if (col == 128) tgt = ash[row];
                else                 tgt = ast[row];
                const float mk = masks[row];
                const float bce = fmaxf(l, 0.0f) - l * tgt + log1pf(__expf(-fabsf(l)));
                lsum += bce * mk;
            }
        }
    }
    for (int o = 32; o > 0; o >>= 1) lsum += __shfl_down(lsum, o, 64);
    if (lane == 0) rbuf[wave] = lsum;
    __syncthreads();
    if (tid == 0) {
        atomicAdd(&accum[0], rbuf[0] + rbuf[1] + rbuf[2] + rbuf[3]);
        __threadfence();
        const unsigned int prev = atomicAdd((unsigned int*)(accum + 2), 1u);
        if (prev == gridDim.x - 1) {   // last block finalizes
            const float s = atomicAdd(&accum[0], 0.0f);
            const float m = atomicAdd(&accum[1], 0.0f);
            out[0] = s / m;
        }
    }
}

extern "C" void kernel_launch(void* const* d_in, const int* in_sizes, int n_in,
                              void* d_out, int out_size, void* d_ws, size_t ws_size,
                              hipStream_t stream) {
    const float* ctx   = (const float*)d_in[0];
    const float* masks = (const float*)d_in[1];
    const float* ash   = (const float*)d_in[2];
    const float* ast   = (const float*)d_in[3];
    const float* sh    = (const float*)d_in[4];
    const float* st    = (const float*)d_in[5];
    const float* oh    = (const float*)d_in[6];
    const float* ot    = (const float*)d_in[7];
    const float* Ws_h  = (const float*)d_in[8];
    const float* bs_h  = (const float*)d_in[9];
    const float* Ws_t  = (const float*)d_in[10];
    const float* bs_t  = (const float*)d_in[11];
    const float* Wo_h  = (const float*)d_in[12];
    const float* bo_h  = (const float*)d_in[13];
    const float* Wo_t  = (const float*)d_in[14];
    const float* bo_t  = (const float*)d_in[15];
    float* out = (float*)d_out;

    char* ws = (char*)d_ws;
    float* accum   = (float*)(ws + 0);                 // [0]=loss, [1]=msum, [2]=counter
    float* rowBias = (float*)(ws + 256);               // [32][160] fp32
    unsigned short* WtG = (unsigned short*)(ws + 256 + 32 * NPAD * 4); // [160][1024] bf16

    hipMemsetAsync(accum, 0, 12, stream);
    aux_kernel<<<TBLK + B_, 256, 0, stream>>>(ctx, sh, st, masks, Wo_h, Wo_t,
                                              Ws_h, Ws_t, bo_h, bo_t, bs_h, bs_t,
                                              WtG, rowBias, accum);
    main_kernel<<<M_ / MT, 256, 0, stream>>>(ctx, WtG, rowBias, masks,
                                             ash, ast, oh, ot, accum, out);
}

// Round 7
// 162.145 us; speedup vs baseline: 1.0732x; 1.0203x over previous
//
#include <hip/hip_runtime.h>

// CASREL loss, B=32,S=512,H=1024,R=64 -> scalar fp32 loss.
// v8: staged-bytes reduction. Evidence v5-v7: time scales with per-chunk
// staged volume (BK=128 doubled per-chunk time exactly), not rounds/occupancy/
// pipelining. Per-CU staging was 896 KB (B=WtG re-read by every block
// dominating). MT 32->64 (grid 256 = 1 block/CU) halves B traffic ->
// 576 KB/CU (0.64x). v7's verified BK=128 staging maps, XOR swizzle,
// fragment offsets and K order kept bit-identical; 8 waves = 4 row-groups
// x 2 col-halves, 5 tiles/wave as before. aux_kernel unchanged.

#define B_  32
#define S_  512
#define H_  1024
#define R_  64
#define M_  (B_ * S_)      // 16384 rows
#define NPAD 160           // 130 valid cols padded
#define NVALID 130
#define BK 128
#define BKP 136            // A LDS pad (shorts)
#define MT 64              // rows per block
#define NCHUNK (H_ / BK)   // 8
#define TBLK 20            // transpose blocks (5 n-tiles x 4 k-tiles)
#define NTHR 512           // 8 waves

typedef __attribute__((ext_vector_type(4))) float  floatx4;
typedef __attribute__((ext_vector_type(8))) short  short8;     // 8 bf16
typedef __attribute__((ext_vector_type(4))) unsigned short u16x4;
typedef __attribute__((ext_vector_type(8))) unsigned short u16x8;

__device__ __forceinline__ unsigned short f2bf(float f) {
    unsigned int u = __float_as_uint(f);
    u = (u + 0x7FFFu + ((u >> 16) & 1u)) >> 16;   // RNE
    return (unsigned short)u;
}

__device__ __forceinline__ u16x8 cvt8u(float4 a, float4 b) {
    u16x8 u;
    u[0] = f2bf(a.x); u[1] = f2bf(a.y); u[2] = f2bf(a.z); u[3] = f2bf(a.w);
    u[4] = f2bf(b.x); u[5] = f2bf(b.y); u[6] = f2bf(b.z); u[7] = f2bf(b.w);
    return u;
}

// ---- K1 (merged): blocks [0,TBLK) transpose WtG; blocks [TBLK,TBLK+B_) subj ----
__global__ __launch_bounds__(256) void aux_kernel(
        const float* __restrict__ ctx, const float* __restrict__ head,
        const float* __restrict__ tail, const float* __restrict__ masks,
        const float* __restrict__ Wo_h, const float* __restrict__ Wo_t,
        const float* __restrict__ Ws_h, const float* __restrict__ Ws_t,
        const float* __restrict__ bo_h, const float* __restrict__ bo_t,
        const float* __restrict__ bs_h, const float* __restrict__ bs_t,
        unsigned short* __restrict__ WtG, float* __restrict__ rowBias,
        float* __restrict__ accum) {
    const int tid = threadIdx.x;
    __shared__ float tr[32][257];      // transpose tile (pad 257: conflict-free)
    __shared__ float subj[H_];
    __shared__ float partS[4][256];
    __shared__ int cnt;
    __shared__ int   sidx[8];
    __shared__ float sw[8];

    if (blockIdx.x < TBLK) {
        const int kt = blockIdx.x / 5, nt = blockIdx.x % 5;
        const int k0 = kt * 256, n0 = nt * 32;
        if (n0 < 128) {
            const float* src = (n0 < 64) ? Wo_h : Wo_t;
            const int cb = n0 & 63;
            const int nn = tid & 31, kk = tid >> 5;   // 8 k-rows per pass
#pragma unroll
            for (int i = 0; i < 32; ++i) {
                const int k = k0 + i * 8 + kk;
                tr[nn][i * 8 + kk] = src[(size_t)k * R_ + cb + nn];
            }
            __syncthreads();
#pragma unroll
            for (int p = 0; p < 4; ++p) {
                const int chunk = p * 256 + tid;
                const int n = chunk >> 5;             // 0..31
                const int kc = (chunk & 31) * 8;
                u16x8 v;
#pragma unroll
                for (int j = 0; j < 8; ++j) v[j] = f2bf(tr[n][kc + j]);
                *(u16x8*)(WtG + (size_t)(n0 + n) * H_ + k0 + kc) = v;
            }
        } else {
#pragma unroll
            for (int p = 0; p < 4; ++p) {
                const int chunk = p * 256 + tid;
                const int n = 128 + (chunk >> 5);
                const int kc = (chunk & 31) * 8;
                u16x8 v;
#pragma unroll
                for (int j = 0; j < 8; ++j) {
                    float f = (n == 128) ? Ws_h[k0 + kc + j]
                            : (n == 129) ? Ws_t[k0 + kc + j] : 0.0f;
                    v[j] = f2bf(f);
                }
                *(u16x8*)(WtG + (size_t)n * H_ + k0 + kc) = v;
            }
        }
        return;
    }

    const int b = blockIdx.x - TBLK;
    if (tid == 0) cnt = 0;
    __syncthreads();
    float msk = 0.0f;
    for (int s = tid; s < S_; s += 256) {
        float w = 0.5f * (head[b * S_ + s] + tail[b * S_ + s]);
        if (w != 0.0f) {
            int i = atomicAdd(&cnt, 1);
            if (i < 8) { sidx[i] = s; sw[i] = w; }
        }
        msk += masks[b * S_ + s];
    }
    for (int o = 32; o > 0; o >>= 1) msk += __shfl_down(msk, o, 64);
    if ((tid & 63) == 0) atomicAdd(&accum[1], msk);
    __syncthreads();
    const int nnz = cnt < 8 ? cnt : 8;
    for (int h = tid; h < H_; h += 256) {
        float a = 0.0f;
        for (int i = 0; i < nnz; i++)
            a += sw[i] * ctx[((size_t)b * S_ + sidx[i]) * H_ + h];
        subj[h] = a;
    }
    __syncthreads();
    {   // rowBias dot: thread = (c-group of 4, k-slice of 128); float4 W loads
        const int cg = tid & 31;
        const int ks = tid >> 5;
        const int c4 = cg * 4;
        const float* W = (c4 < 64) ? Wo_h : Wo_t;
        const int cc = c4 & 63;
        const int kk0 = ks * 128;
        float ax = 0.f, ay = 0.f, az = 0.f, aw2 = 0.f;
#pragma unroll 4
        for (int k = kk0; k < kk0 + 128; ++k) {
            const float4 w = *(const float4*)(W + (size_t)k * R_ + cc);
            const float sv = subj[k];
            ax += sv * w.x; ay += sv * w.y; az += sv * w.z; aw2 += sv * w.w;
        }
        partS[0][tid] = ax; partS[1][tid] = ay;
        partS[2][tid] = az; partS[3][tid] = aw2;
    }
    __syncthreads();
    if (tid < NPAD) {
        float bias = tid < 64  ? bo_h[tid]
                   : tid < 128 ? bo_t[tid - 64]
                   : tid == 128 ? bs_h[0]
                   : tid == 129 ? bs_t[0] : 0.0f;
        float a2 = 0.0f;
        if (tid < 128) {
            const int g = tid >> 2, j = tid & 3;
#pragma unroll
            for (int s = 0; s < 8; ++s) a2 += partS[j][s * 32 + g];
        }
        rowBias[b * NPAD + tid] = bias + a2;
    }
}

// ---- K2: MT=64, 8-wave, BK=128 GEMM + BCE + masked reduction + finalize ----
__global__ __launch_bounds__(NTHR, 2) void main_kernel(
        const float* __restrict__ ctx, const unsigned short* __restrict__ WtG,
        const float* __restrict__ rowBias, const float* __restrict__ masks,
        const float* __restrict__ ash, const float* __restrict__ ast,
        const float* __restrict__ oh, const float* __restrict__ ot,
        float* __restrict__ accum, float* __restrict__ out) {
    __shared__ __align__(16) unsigned short Asm[MT * BKP];   // 17.4 KB
    __shared__ __align__(16) unsigned short Bsm[NPAD * BK];  // 40 KB
    __shared__ float rbuf[8];

    const int tid  = threadIdx.x;
    const int gm0  = blockIdx.x * MT;
    const int b    = gm0 >> 9;                // 512 rows per batch (MT=64 divides)
    const int wave = tid >> 6, lane = tid & 63;
    const int wm = wave & 3;            // row group (16 rows), 0..3
    const int wn = wave >> 2;           // col half (80 cols = 5 tiles), 0..1
    const int lr = lane & 15, q = lane >> 4;   // q in 0..3

    // A staging: thread -> row ar = tid>>3 (0..63), 16 floats at col (tid&7)*16
    const int ar = tid >> 3, as_ = (tid & 7) * 16;
    const float* aSrc = ctx + (size_t)(gm0 + ar) * H_ + as_;
    unsigned short* aDst = &Asm[ar * BKP + as_];

    // B staging: rows {br, br+64, br+128(if tid<256)}, 16 shorts at (tid&7)*16
    // LDS layout: [row][128] shorts, byte col XOR-swizzled by ((row&7)<<4)
    const int br = tid >> 3, bs0 = (tid & 7) * 16;   // shorts
    const unsigned short* bSrc = WtG + (size_t)br * H_ + bs0;
    const int bswz = (br & 7) << 4;                  // rows differ by 64 -> same swz
    char* bDstB = (char*)Bsm + br * 256;             // + ((bytecol)^bswz)
    const bool bp2 = (tid < 256);                    // wave-uniform (waves 0-3)

    // compute-side fragment offsets
    const int aOff = (wm * 16 + lr) * BKP + q * 8;   // shorts
    int bOff[5];
#pragma unroll
    for (int tt = 0; tt < 5; ++tt) {
        const int row = wn * 80 + tt * 16 + lr;
        bOff[tt] = row * 256 + ((q * 16) ^ ((row & 7) << 4));   // bytes; ^(kk<<1) per substep
    }

    floatx4 acc[5];
#pragma unroll
    for (int tt = 0; tt < 5; ++tt) acc[tt] = (floatx4){0.f, 0.f, 0.f, 0.f};

    // staging registers for one chunk
    float4 aR[4];
    u16x8  bR[6];

#define LOADREGS(k0) do {                                                      \
        _Pragma("unroll")                                                      \
        for (int i = 0; i < 4; ++i)                                            \
            aR[i] = *(const float4*)(aSrc + (k0) + i * 4);                     \
        bR[0] = *(const u16x8*)(bSrc + (k0));                                  \
        bR[1] = *(const u16x8*)(bSrc + (k0) + 8);                              \
        bR[2] = *(const u16x8*)(bSrc + (size_t)64 * H_ + (k0));                \
        bR[3] = *(const u16x8*)(bSrc + (size_t)64 * H_ + (k0) + 8);            \
        if (bp2) {                                                             \
            bR[4] = *(const u16x8*)(bSrc + (size_t)128 * H_ + (k0));           \
            bR[5] = *(const u16x8*)(bSrc + (size_t)128 * H_ + (k0) + 8);       \
        }                                                                      \
    } while (0)

#define WRITE_LDS() do {                                                       \
        *(u16x8*)(aDst)     = cvt8u(aR[0], aR[1]);                             \
        *(u16x8*)(aDst + 8) = cvt8u(aR[2], aR[3]);                             \
        *(u16x8*)(bDstB + ((bs0 * 2)      ^ bswz)) = bR[0];                    \
        *(u16x8*)(bDstB + ((bs0 * 2 + 16) ^ bswz)) = bR[1];                    \
        *(u16x8*)(bDstB + 64 * 256 + ((bs0 * 2)      ^ bswz)) = bR[2];         \
        *(u16x8*)(bDstB + 64 * 256 + ((bs0 * 2 + 16) ^ bswz)) = bR[3];         \
        if (bp2) {                                                             \
            *(u16x8*)(bDstB + 128 * 256 + ((bs0 * 2)      ^ bswz)) = bR[4];    \
            *(u16x8*)(bDstB + 128 * 256 + ((bs0 * 2 + 16) ^ bswz)) = bR[5];    \
        }                                                                      \
    } while (0)

    LOADREGS(0);
    for (int t = 0; t < NCHUNK; ++t) {
        __syncthreads();                 // (a) prior chunk's LDS reads done
        WRITE_LDS();
        if (t < NCHUNK - 1) LOADREGS((t + 1) * BK);   // issue next loads now
        __syncthreads();                 // (b) LDS writes visible
        // compute chunk t (loads for t+1 in flight under this)
#pragma unroll
        for (int kk = 0; kk < BK; kk += 32) {
            short8 afr = *(const short8*)&Asm[aOff + kk];
#pragma unroll
            for (int tt = 0; tt < 5; ++tt) {
                short8 bfr = *(const short8*)((const char*)Bsm + (bOff[tt] ^ (kk << 1)));
                acc[tt] = __builtin_amdgcn_mfma_f32_16x16x32_bf16(afr, bfr, acc[tt], 0, 0, 0);
            }
        }
    }
#undef LOADREGS
#undef WRITE_LDS

    // epilogue: logits -> BCE * mask -> sum
    float lsum = 0.0f;
#pragma unroll
    for (int tt = 0; tt < 5; ++tt) {
        const int col = wn * 80 + tt * 16 + lr;
        if (col < NVALID) {
            const float rb = rowBias[b * NPAD + col];
#pragma unroll
            for (int i = 0; i < 4; ++i) {
                const int row = gm0 + wm * 16 + q * 4 + i;
                const float l = acc[tt][i] + rb;
                float tgt;
                if (col < 64)        tgt = oh[(size_t)row * R_ + col];
                else if (col < 128)  tgt = ot[(size_t)row * R_ + (col - 64)];
                else if (col == 128) tgt = ash[row];
                else                 tgt = ast[row];
                const float mk = masks[row];
                const float bce = fmaxf(l, 0.0f) - l * tgt + log1pf(__expf(-fabsf(l)));
                lsum += bce * mk;
            }
        }
    }
    for (int o = 32; o > 0; o >>= 1) lsum += __shfl_down(lsum, o, 64);
    if (lane == 0) rbuf[wave] = lsum;
    __syncthreads();
    if (tid == 0) {
        float s0 = 0.0f;
#pragma unroll
        for (int w = 0; w < 8; ++w) s0 += rbuf[w];
        atomicAdd(&accum[0], s0);
        __threadfence();
        const unsigned int prev = atomicAdd((unsigned int*)(accum + 2), 1u);
        if (prev == gridDim.x - 1) {   // last block finalizes
            const float s = atomicAdd(&accum[0], 0.0f);
            const float m = atomicAdd(&accum[1], 0.0f);
            out[0] = s / m;
        }
    }
}

extern "C" void kernel_launch(void* const* d_in, const int* in_sizes, int n_in,
                              void* d_out, int out_size, void* d_ws, size_t ws_size,
                              hipStream_t stream) {
    const float* ctx   = (const float*)d_in[0];
    const float* masks = (const float*)d_in[1];
    const float* ash   = (const float*)d_in[2];
    const float* ast   = (const float*)d_in[3];
    const float* sh    = (const float*)d_in[4];
    const float* st    = (const float*)d_in[5];
    const float* oh    = (const float*)d_in[6];
    const float* ot    = (const float*)d_in[7];
    const float* Ws_h  = (const float*)d_in[8];
    const float* bs_h  = (const float*)d_in[9];
    const float* Ws_t  = (const float*)d_in[10];
    const float* bs_t  = (const float*)d_in[11];
    const float* Wo_h  = (const float*)d_in[12];
    const float* bo_h  = (const float*)d_in[13];
    const float* Wo_t  = (const float*)d_in[14];
    const float* bo_t  = (const float*)d_in[15];
    float* out = (float*)d_out;

    char* ws = (char*)d_ws;
    float* accum   = (float*)(ws + 0);                 // [0]=loss, [1]=msum, [2]=counter
    float* rowBias = (float*)(ws + 256);               // [32][160] fp32
    unsigned short* WtG = (unsigned short*)(ws + 256 + 32 * NPAD * 4); // [160][1024] bf16

    hipMemsetAsync(accum, 0, 12, stream);
    aux_kernel<<<TBLK + B_, 256, 0, stream>>>(ctx, sh, st, masks, Wo_h, Wo_t,
                                              Ws_h, Ws_t, bo_h, bo_t, bs_h, bs_t,
                                              WtG, rowBias, accum);
    main_kernel<<<M_ / MT, NTHR, 0, stream>>>(ctx, WtG, rowBias, masks,
                                              ash, ast, oh, ot, accum, out);
}